// Round 1
// baseline (106.033 us; speedup 1.0000x reference)
//
#include <hip/hip_runtime.h>

// Problem constants
#define BATCH 1024
#define NIN   512
#define NOUT  512
#define NB    11
#define KSPLINE (NIN * NB)        // 5632
#define KDIM    (KSPLINE + NIN)   // 6144
#define SPLITS  8
#define BK      32

typedef short bf16x8 __attribute__((ext_vector_type(8)));
typedef float f32x4  __attribute__((ext_vector_type(4)));

__device__ __forceinline__ unsigned short f2bf(float f) {
  unsigned u = __float_as_uint(f);
  u += 0x7fff + ((u >> 16) & 1);   // RNE to bf16
  return (unsigned short)(u >> 16);
}

// K1: per (b,i): cubic Cox-de Boor basis (11 values) + silu(x) -> A [1024][6144] bf16
// knots t[j] = -5.25 + 0.75*j, j=0..14
__global__ __launch_bounds__(256) void k_basis(const float* __restrict__ x,
                                               unsigned short* __restrict__ A) {
  int tid = blockIdx.x * 256 + threadIdx.x;  // 0 .. 1024*512-1
  float xv = x[tid];
  float B[14];
#pragma unroll
  for (int j = 0; j < 14; ++j) {
    float t0 = -5.25f + 0.75f * (float)j;
    float t1 = t0 + 0.75f;
    B[j] = (xv >= t0 && xv < t1) ? 1.0f : 0.0f;
  }
#pragma unroll
  for (int d = 1; d <= 3; ++d) {
    float inv = 1.0f / (0.75f * (float)d);
#pragma unroll
    for (int j = 0; j <= 13 - d; ++j) {
      float tj   = -5.25f + 0.75f * (float)j;
      float tjd1 = tj + 0.75f * (float)(d + 1);
      B[j] = (xv - tj) * inv * B[j] + (tjd1 - xv) * inv * B[j + 1];
    }
  }
  int b = tid >> 9, i = tid & 511;
  unsigned short* row = A + (size_t)b * KDIM;
#pragma unroll
  for (int j = 0; j < NB; ++j) row[i * NB + j] = f2bf(B[j]);
  float sig = 1.0f / (1.0f + __expf(-xv));
  row[KSPLINE + i] = f2bf(xv * sig);
}

// K2: Bt[o][i*11+k] = c[(i*512+o)*11+k] * w[i*512+o]; Bt[o][5632+i] = w[i*512+o]
__global__ __launch_bounds__(256) void k_coef(const float* __restrict__ c,
                                              const float* __restrict__ w,
                                              unsigned short* __restrict__ Bt) {
  int o  = blockIdx.x;                          // 0..511
  int kk = blockIdx.y * 256 + threadIdx.x;      // 0..6143
  float v;
  if (kk < KSPLINE) {
    int i = kk / NB;
    int k = kk - i * NB;
    v = c[(size_t)(i * NOUT + o) * NB + k] * w[i * NOUT + o];
  } else {
    int i = kk - KSPLINE;
    v = w[i * NOUT + o];
  }
  Bt[(size_t)o * KDIM + kk] = f2bf(v);
}

// K3: split-K GEMM: out_part[split][b][o] = A[b, k0:k0+kchunk] . Bt[o, k0:k0+kchunk]
// 128x128 block tile, 4 waves 2x2, each wave 64x64 via 4x4 grid of 16x16x32 bf16 MFMA.
__global__ __launch_bounds__(256) void k_gemm(const unsigned short* __restrict__ A,
                                              const unsigned short* __restrict__ Bt,
                                              float* __restrict__ out,
                                              int kchunk) {
  __shared__ unsigned short As[128 * BK];  // 8 KB
  __shared__ unsigned short Bs[128 * BK];  // 8 KB
  const int tid  = threadIdx.x;
  const int lane = tid & 63, wave = tid >> 6;
  const int wr = wave >> 1, wc = wave & 1;
  const int mbase = blockIdx.x * 128, nbase = blockIdx.y * 128;
  const int split = blockIdx.z;
  const int k0 = split * kchunk;

  f32x4 acc[4][4] = {};

  const int mrow = lane & 15;
  const int kq   = (lane >> 4) * 8;

  for (int kk = k0; kk < k0 + kchunk; kk += BK) {
    // stage A and Bt tiles: 128 rows x 32 bf16 (64 B/row = 4 x 16B chunks), 512 chunks each
#pragma unroll
    for (int it = 0; it < 2; ++it) {
      int ch  = it * 256 + tid;
      int row = ch >> 2, col = (ch & 3) * 8;
      const unsigned short* ga = A  + (size_t)(mbase + row) * KDIM + kk + col;
      const unsigned short* gb = Bt + (size_t)(nbase + row) * KDIM + kk + col;
      unsigned short* la = As + (it * 256 + wave * 64) * 8;  // lane writes base + lane*16
      unsigned short* lb = Bs + (it * 256 + wave * 64) * 8;
      __builtin_amdgcn_global_load_lds((__attribute__((address_space(1))) const void*)ga,
                                       (__attribute__((address_space(3))) void*)la, 16, 0, 0);
      __builtin_amdgcn_global_load_lds((__attribute__((address_space(1))) const void*)gb,
                                       (__attribute__((address_space(3))) void*)lb, 16, 0, 0);
    }
    __syncthreads();

    bf16x8 af[4], bfr[4];
#pragma unroll
    for (int mt = 0; mt < 4; ++mt)
      af[mt] = *(const bf16x8*)&As[(wr * 64 + mt * 16 + mrow) * BK + kq];
#pragma unroll
    for (int nt = 0; nt < 4; ++nt)
      bfr[nt] = *(const bf16x8*)&Bs[(wc * 64 + nt * 16 + mrow) * BK + kq];
#pragma unroll
    for (int mt = 0; mt < 4; ++mt)
#pragma unroll
      for (int nt = 0; nt < 4; ++nt)
        acc[mt][nt] = __builtin_amdgcn_mfma_f32_16x16x32_bf16(af[mt], bfr[nt], acc[mt][nt], 0, 0, 0);
    __syncthreads();
  }

  // epilogue: C/D layout col = lane&15, row = (lane>>4)*4 + reg
  const int rq = (lane >> 4) * 4;
#pragma unroll
  for (int mt = 0; mt < 4; ++mt)
#pragma unroll
    for (int nt = 0; nt < 4; ++nt) {
      int colg = nbase + wc * 64 + nt * 16 + mrow;
#pragma unroll
      for (int r = 0; r < 4; ++r) {
        int rowg = mbase + wr * 64 + mt * 16 + rq + r;
        out[((size_t)split * BATCH + rowg) * NOUT + colg] = acc[mt][nt][r];
      }
    }
}

// K4: out = sum over 8 split partials
__global__ __launch_bounds__(256) void k_reduce(const float* __restrict__ part,
                                                float* __restrict__ out) {
  int t = blockIdx.x * 256 + threadIdx.x;  // 0..131071 (float4 index)
  f32x4 s = ((const f32x4*)part)[t];
#pragma unroll
  for (int sp = 1; sp < SPLITS; ++sp)
    s += ((const f32x4*)part)[(size_t)sp * (BATCH * NOUT / 4) + t];
  ((f32x4*)out)[t] = s;
}

extern "C" void kernel_launch(void* const* d_in, const int* in_sizes, int n_in,
                              void* d_out, int out_size, void* d_ws, size_t ws_size,
                              hipStream_t stream) {
  const float* x = (const float*)d_in[0];
  const float* c = (const float*)d_in[1];
  const float* w = (const float*)d_in[2];
  float* out = (float*)d_out;

  unsigned short* A  = (unsigned short*)d_ws;
  unsigned short* Bt = A + (size_t)BATCH * KDIM;
  float* part = (float*)((char*)d_ws + ((size_t)BATCH + NOUT) * KDIM * 2);

  size_t need = ((size_t)BATCH + NOUT) * KDIM * 2 + (size_t)SPLITS * BATCH * NOUT * 4;

  k_basis<<<dim3((BATCH * NIN) / 256), 256, 0, stream>>>(x, A);
  k_coef<<<dim3(NOUT, KDIM / 256), 256, 0, stream>>>(c, w, Bt);
  if (ws_size >= need) {
    k_gemm<<<dim3(8, 4, SPLITS), 256, 0, stream>>>(A, Bt, part, KDIM / SPLITS);
    k_reduce<<<dim3((BATCH * NOUT / 4) / 256), 256, 0, stream>>>(part, out);
  } else {
    // fallback: no room for partials -> single-pass GEMM straight to out (slower, correct)
    k_gemm<<<dim3(8, 4, 1), 256, 0, stream>>>(A, Bt, out, KDIM);
  }
}

// Round 2
// 99.377 us; speedup vs baseline: 1.0670x; 1.0670x over previous
//
#include <hip/hip_runtime.h>

// Problem constants
#define BATCH 1024
#define NIN   512
#define NOUT  512
#define NB    11
#define KSPLINE (NIN * NB)        // 5632
#define KDIM    (KSPLINE + NIN)   // 6144
#define SPLITS  16
#define BK      64
#define KCHUNK  (KDIM / SPLITS)   // 384

typedef short bf16x8 __attribute__((ext_vector_type(8)));
typedef float f32x4  __attribute__((ext_vector_type(4)));

__device__ __forceinline__ unsigned short f2bf(float f) {
  unsigned u = __float_as_uint(f);
  u += 0x7fff + ((u >> 16) & 1);   // RNE to bf16
  return (unsigned short)(u >> 16);
}

// K1 fused prep:
//  blocks [0,2048):    basis+silu -> A [1024][6144] bf16
//  blocks [2048,14336): Bt[o][i*11+k] = c[i*5632+o*11+k]*w[i*512+o]; Bt[o][5632+i]=w[i*512+o]
//  (o = fastest-varying so same-kk blocks with adjacent o share c cache lines)
__global__ __launch_bounds__(256) void k_prep(const float* __restrict__ x,
                                              const float* __restrict__ c,
                                              const float* __restrict__ w,
                                              unsigned short* __restrict__ A,
                                              unsigned short* __restrict__ Bt) {
  int blk = blockIdx.x;
  if (blk < 2048) {
    int tid = blk * 256 + threadIdx.x;  // 0 .. 1024*512-1
    float xv = x[tid];
    float B[14];
#pragma unroll
    for (int j = 0; j < 14; ++j) {
      float t0 = -5.25f + 0.75f * (float)j;
      float t1 = t0 + 0.75f;
      B[j] = (xv >= t0 && xv < t1) ? 1.0f : 0.0f;
    }
#pragma unroll
    for (int d = 1; d <= 3; ++d) {
      float inv = 1.0f / (0.75f * (float)d);
#pragma unroll
      for (int j = 0; j <= 13 - d; ++j) {
        float tj   = -5.25f + 0.75f * (float)j;
        float tjd1 = tj + 0.75f * (float)(d + 1);
        B[j] = (xv - tj) * inv * B[j] + (tjd1 - xv) * inv * B[j + 1];
      }
    }
    int b = tid >> 9, i = tid & 511;
    unsigned short* row = A + (size_t)b * KDIM;
#pragma unroll
    for (int j = 0; j < NB; ++j) row[i * NB + j] = f2bf(B[j]);
    float sig = 1.0f / (1.0f + __expf(-xv));
    row[KSPLINE + i] = f2bf(xv * sig);
  } else {
    int bc = blk - 2048;
    int o  = bc & 511;                            // fastest
    int kk = (bc >> 9) * 256 + threadIdx.x;       // 0..6143
    float v;
    if (kk < KSPLINE) {
      int i = kk / NB;
      int k = kk - i * NB;
      v = c[(size_t)i * KSPLINE + o * NB + k] * w[i * NOUT + o];
    } else {
      int i = kk - KSPLINE;
      v = w[i * NOUT + o];
    }
    Bt[(size_t)o * KDIM + kk] = f2bf(v);
  }
}

// K2: split-K GEMM: part[split][b][o] += A[b, ks..] . Bt[o, ks..]
// 128x128 block tile, 4 waves 2x2, wave = 64x64 via 4x4 of 16x16x32 bf16 MFMA.
// BK=64 (2 k-steps per stage), XOR-swizzled LDS to kill ds_read_b128 bank conflicts.
__global__ __launch_bounds__(256) void k_gemm(const unsigned short* __restrict__ A,
                                              const unsigned short* __restrict__ Bt,
                                              float* __restrict__ out,
                                              int kchunk) {
  __shared__ unsigned short As[128 * BK];  // 16 KB
  __shared__ unsigned short Bs[128 * BK];  // 16 KB
  const int tid  = threadIdx.x;
  const int lane = tid & 63, wave = tid >> 6;
  const int wr = wave >> 1, wc = wave & 1;
  const int mbase = blockIdx.x * 128, nbase = blockIdx.y * 128;
  const int split = blockIdx.z;
  const int k0 = split * kchunk;

  f32x4 acc[4][4] = {};

  const int mrow = lane & 15;
  const int kq   = (lane >> 4) * 8;   // k-offset of this quarter-wave's frag
  const int swz  = mrow & 7;          // row-dependent XOR for LDS de-swizzle

  for (int kk = k0; kk < k0 + kchunk; kk += BK) {
    // stage A,Bt tiles: 128 rows x 64 bf16 = 128 B/row = 8 x 16B chunks; 1024 chunks/tile.
    // LDS dest is forced to base+lane*16, so swizzle the GLOBAL column: chunk at LDS
    // (row, cg) holds global column group cg ^ (row&7).
#pragma unroll
    for (int it = 0; it < 4; ++it) {
      int ch  = it * 256 + tid;
      int row = ch >> 3;
      int cgl = ch & 7;
      int col = (cgl ^ (row & 7)) * 8;
      const unsigned short* ga = A  + (size_t)(mbase + row) * KDIM + kk + col;
      const unsigned short* gb = Bt + (size_t)(nbase + row) * KDIM + kk + col;
      unsigned short* la = As + (it * 256 + wave * 64) * 8;
      unsigned short* lb = Bs + (it * 256 + wave * 64) * 8;
      __builtin_amdgcn_global_load_lds((__attribute__((address_space(1))) const void*)ga,
                                       (__attribute__((address_space(3))) void*)la, 16, 0, 0);
      __builtin_amdgcn_global_load_lds((__attribute__((address_space(1))) const void*)gb,
                                       (__attribute__((address_space(3))) void*)lb, 16, 0, 0);
    }
    __syncthreads();

#pragma unroll
    for (int ks = 0; ks < BK; ks += 32) {
      bf16x8 af[4], bfr[4];
#pragma unroll
      for (int mt = 0; mt < 4; ++mt) {
        int row = wr * 64 + mt * 16 + mrow;
        int cg  = ((ks + kq) >> 3) ^ swz;
        af[mt] = *(const bf16x8*)&As[row * BK + cg * 8];
      }
#pragma unroll
      for (int nt = 0; nt < 4; ++nt) {
        int row = wc * 64 + nt * 16 + mrow;
        int cg  = ((ks + kq) >> 3) ^ swz;
        bfr[nt] = *(const bf16x8*)&Bs[row * BK + cg * 8];
      }
#pragma unroll
      for (int mt = 0; mt < 4; ++mt)
#pragma unroll
        for (int nt = 0; nt < 4; ++nt)
          acc[mt][nt] = __builtin_amdgcn_mfma_f32_16x16x32_bf16(af[mt], bfr[nt], acc[mt][nt], 0, 0, 0);
    }
    __syncthreads();
  }

  // epilogue: C/D layout col = lane&15, row = (lane>>4)*4 + reg
  const int rq = (lane >> 4) * 4;
#pragma unroll
  for (int mt = 0; mt < 4; ++mt)
#pragma unroll
    for (int nt = 0; nt < 4; ++nt) {
      int colg = nbase + wc * 64 + nt * 16 + mrow;
#pragma unroll
      for (int r = 0; r < 4; ++r) {
        int rowg = mbase + wr * 64 + mt * 16 + rq + r;
        out[((size_t)split * BATCH + rowg) * NOUT + colg] = acc[mt][nt][r];
      }
    }
}

// K3: out = sum over SPLITS partials
__global__ __launch_bounds__(256) void k_reduce(const float* __restrict__ part,
                                                float* __restrict__ out) {
  int t = blockIdx.x * 256 + threadIdx.x;  // float4 index
  f32x4 s = ((const f32x4*)part)[t];
#pragma unroll
  for (int sp = 1; sp < SPLITS; ++sp)
    s += ((const f32x4*)part)[(size_t)sp * (BATCH * NOUT / 4) + t];
  ((f32x4*)out)[t] = s;
}

extern "C" void kernel_launch(void* const* d_in, const int* in_sizes, int n_in,
                              void* d_out, int out_size, void* d_ws, size_t ws_size,
                              hipStream_t stream) {
  const float* x = (const float*)d_in[0];
  const float* c = (const float*)d_in[1];
  const float* w = (const float*)d_in[2];
  float* out = (float*)d_out;

  unsigned short* A  = (unsigned short*)d_ws;
  unsigned short* Bt = A + (size_t)BATCH * KDIM;
  float* part = (float*)((char*)d_ws + ((size_t)BATCH + NOUT) * KDIM * 2);

  size_t need = ((size_t)BATCH + NOUT) * KDIM * 2 + (size_t)SPLITS * BATCH * NOUT * 4;

  k_prep<<<dim3(2048 + 512 * (KDIM / 256)), 256, 0, stream>>>(x, c, w, A, Bt);
  if (ws_size >= need) {
    k_gemm<<<dim3(8, 4, SPLITS), 256, 0, stream>>>(A, Bt, part, KCHUNK);
    k_reduce<<<dim3((BATCH * NOUT / 4) / 256), 256, 0, stream>>>(part, out);
  } else {
    // fallback: single-pass GEMM straight to out (slower, correct)
    k_gemm<<<dim3(8, 4, 1), 256, 0, stream>>>(A, Bt, out, KDIM);
  }
}